// Round 2
// baseline (279.868 us; speedup 1.0000x reference)
//
#include <hip/hip_runtime.h>

// Problem constants (B,T,C,H) = (4, 4096, 768, 64)
#define Bn 4
#define Tn 4096
#define Cn 768
#define Hn 64
#define Mn (Bn * Tn)                    // 16384 rows
#define SCALE_ 0.036084391824351615f    // 768^-0.5  (reference scales by C^-0.5)

typedef __bf16 bf16x8 __attribute__((ext_vector_type(8)));
typedef float f32x4 __attribute__((ext_vector_type(4)));
typedef unsigned short us8 __attribute__((ext_vector_type(8)));

union U8 { us8 u; bf16x8 b; };

#define MFMA16(a, b, c) __builtin_amdgcn_mfma_f32_16x16x32_bf16((a), (b), (c), 0, 0, 0)

__device__ __forceinline__ unsigned short f2bf(float f) {
  unsigned u = __float_as_uint(f);
  u += 0x7fffu + ((u >> 16) & 1u);   // round-to-nearest-even
  return (unsigned short)(u >> 16);
}

// ---------------------------------------------------------------------------
// Kernel 0: WT[n][c] bf16, n in [0,192): 0-63 = Wq cols, 64-127 = Wk, 128-191 = Wv
// ---------------------------------------------------------------------------
__global__ __launch_bounds__(256) void wt_prep(const float* __restrict__ Wq,
                                               const float* __restrict__ Wk,
                                               const float* __restrict__ Wv,
                                               unsigned short* __restrict__ WT) {
  int n = blockIdx.x;  // 0..191
  const float* src = (n < 64) ? Wq : (n < 128) ? Wk : Wv;
  int h = n & 63;
  for (int c = threadIdx.x; c < Cn; c += 256)
    WT[n * Cn + c] = f2bf(src[c * Hn + h]);
}

// ---------------------------------------------------------------------------
// Kernel 1: QKV projection. grid = Mn/64 blocks x 256 thr (4 waves x 16 rows).
// Each wave: 16 rows x 192 cols, K=768 in 12 chunks of 64.
// A-frag: x rows direct from global (fp32 -> bf16); B-frag: WT from L2.
// MFMA 16x16x32 layout: lane = 16*bq + r;
//   A: lane holds A[r][8*bq + j]; B: lane holds B[8*bq + j][r];
//   D: lane holds D[4*bq + j][r]   (m89-verified C/D mapping)
// ---------------------------------------------------------------------------
__global__ __launch_bounds__(256) void proj(const float* __restrict__ x,
                                            const unsigned short* __restrict__ WT,
                                            unsigned short* __restrict__ qkv) {
  int tid = threadIdx.x;
  int wv = tid >> 6, lane = tid & 63, r = lane & 15, bq = lane >> 4;
  int m0 = blockIdx.x * 64 + wv * 16;

  f32x4 acc[12];
#pragma unroll
  for (int i = 0; i < 12; i++) acc[i] = (f32x4){0.f, 0.f, 0.f, 0.f};

  const float* xrow = x + (long)(m0 + r) * Cn;

  for (int kc = 0; kc < 12; kc++) {
    U8 a[2];
#pragma unroll
    for (int ks = 0; ks < 2; ks++) {
      const float* p = xrow + kc * 64 + ks * 32 + bq * 8;
      f32x4 f0 = *(const f32x4*)p;
      f32x4 f1 = *(const f32x4*)(p + 4);
      us8 uu;
      uu[0] = f2bf(f0[0]); uu[1] = f2bf(f0[1]); uu[2] = f2bf(f0[2]); uu[3] = f2bf(f0[3]);
      uu[4] = f2bf(f1[0]); uu[5] = f2bf(f1[1]); uu[6] = f2bf(f1[2]); uu[7] = f2bf(f1[3]);
      a[ks].u = uu;
    }
#pragma unroll
    for (int nt = 0; nt < 12; nt++) {
      const unsigned short* wp = WT + (long)(nt * 16 + r) * Cn + kc * 64 + bq * 8;
      U8 b0, b1;
      b0.u = *(const us8*)wp;
      b1.u = *(const us8*)(wp + 32);
      acc[nt] = MFMA16(a[0].b, b0.b, acc[nt]);
      acc[nt] = MFMA16(a[1].b, b1.b, acc[nt]);
    }
  }
#pragma unroll
  for (int nt = 0; nt < 12; nt++) {
    unsigned short* outp = qkv + (long)(nt >> 2) * Mn * Hn;  // 0:q 1:k 2:v
    int ncol = (nt & 3) * 16 + r;
#pragma unroll
    for (int j = 0; j < 4; j++) {
      int m = m0 + bq * 4 + j;
      outp[(long)m * Hn + ncol] = f2bf(acc[nt][j]);
    }
  }
}

// ---------------------------------------------------------------------------
// Kernel 2: flash attention. grid (Tn/64, Bn) x 256 thr. 64 q-rows/block,
// KV tiles of 64 staged in LDS. Online softmax per q-row (16-lane shfl_xor
// reductions). P staged via LDS for the PV A-operand. Key-side padding mask.
// LDS row stride 88 elems (176 B): 16B-aligned for ds_read_b128, 2-way
// bank conflict only.
// ---------------------------------------------------------------------------
#define LSTR 88

__global__ __launch_bounds__(256) void attn(const unsigned short* __restrict__ qkv,
                                            const int* __restrict__ amask,
                                            float* __restrict__ out) {
  __shared__ unsigned short K_lds[64 * LSTR];
  __shared__ unsigned short VT_lds[64 * LSTR];
  __shared__ unsigned short P_lds[64 * LSTR];
  __shared__ int m_lds[64];

  int tid = threadIdx.x;
  int wv = tid >> 6, lane = tid & 63, r = lane & 15, bq = lane >> 4;
  int bidx = blockIdx.y;
  int q0 = blockIdx.x * 64;
  long base = (long)bidx * Tn;

  const unsigned short* q_ws = qkv;
  const unsigned short* k_ws = qkv + (long)Mn * Hn;
  const unsigned short* v_ws = qkv + 2L * Mn * Hn;

  // Q fragments (hoisted; rows wv*16 + r)
  U8 qf[2];
  {
    const unsigned short* qp = q_ws + (base + q0 + wv * 16 + r) * Hn + bq * 8;
    qf[0].u = *(const us8*)qp;
    qf[1].u = *(const us8*)(qp + 32);
  }

  float mrun[4], lrun[4];
  f32x4 acc[4];
#pragma unroll
  for (int j = 0; j < 4; j++) { mrun[j] = -1e30f; lrun[j] = 0.f; }
#pragma unroll
  for (int nt = 0; nt < 4; nt++) acc[nt] = (f32x4){0.f, 0.f, 0.f, 0.f};

  for (int kv0 = 0; kv0 < Tn; kv0 += 64) {
    __syncthreads();  // previous iteration's PV reads done before restaging
    // stage K (row-major) and V (transposed) tiles: 64 x 64 bf16 each
#pragma unroll
    for (int it = 0; it < 2; it++) {
      int vid = tid + it * 256;
      int row = vid >> 3, cb = vid & 7;
      *(us8*)(&K_lds[row * LSTR + cb * 8]) =
          *(const us8*)(k_ws + (base + kv0 + row) * Hn + cb * 8);
      us8 vvv = *(const us8*)(v_ws + (base + kv0 + row) * Hn + cb * 8);
#pragma unroll
      for (int e = 0; e < 8; e++)
        VT_lds[(cb * 8 + e) * LSTR + row] = vvv[e];
    }
    if (tid < 64) m_lds[tid] = amask[base + kv0 + tid];
    __syncthreads();

    // S = Q K^T for this wave's 16 q-rows x 64 keys
    f32x4 s[4];
#pragma unroll
    for (int kt = 0; kt < 4; kt++) {
      const unsigned short* kp = &K_lds[(kt * 16 + r) * LSTR + bq * 8];
      U8 b0, b1;
      b0.u = *(const us8*)kp;
      b1.u = *(const us8*)(kp + 32);
      f32x4 z = (f32x4){0.f, 0.f, 0.f, 0.f};
      z = MFMA16(qf[0].b, b0.b, z);
      z = MFMA16(qf[1].b, b1.b, z);
      s[kt] = z;
    }

    // scale + key mask, per-row max
    float pm[4];
#pragma unroll
    for (int j = 0; j < 4; j++) pm[j] = -3.0e38f;
#pragma unroll
    for (int kt = 0; kt < 4; kt++) {
      bool dead = (m_lds[kt * 16 + r] == 0);
#pragma unroll
      for (int j = 0; j < 4; j++) {
        float sv = dead ? -3.0e38f : s[kt][j] * SCALE_;
        s[kt][j] = sv;
        pm[j] = fmaxf(pm[j], sv);
      }
    }
#pragma unroll
    for (int j = 0; j < 4; j++) {
      pm[j] = fmaxf(pm[j], __shfl_xor(pm[j], 1));
      pm[j] = fmaxf(pm[j], __shfl_xor(pm[j], 2));
      pm[j] = fmaxf(pm[j], __shfl_xor(pm[j], 4));
      pm[j] = fmaxf(pm[j], __shfl_xor(pm[j], 8));
    }
    float alpha[4], ps[4];
#pragma unroll
    for (int j = 0; j < 4; j++) {
      float mn = fmaxf(mrun[j], pm[j]);   // mrun floored at -1e30: no inf-inf
      alpha[j] = __expf(mrun[j] - mn);
      mrun[j] = mn;
      ps[j] = 0.f;
    }
#pragma unroll
    for (int kt = 0; kt < 4; kt++)
#pragma unroll
      for (int j = 0; j < 4; j++) {
        float p = __expf(s[kt][j] - mrun[j]);  // masked: exp(-3e38) -> 0
        s[kt][j] = p;
        ps[j] += p;
      }
#pragma unroll
    for (int j = 0; j < 4; j++) {
      ps[j] += __shfl_xor(ps[j], 1);
      ps[j] += __shfl_xor(ps[j], 2);
      ps[j] += __shfl_xor(ps[j], 4);
      ps[j] += __shfl_xor(ps[j], 8);
      lrun[j] = lrun[j] * alpha[j] + ps[j];
    }
#pragma unroll
    for (int nt = 0; nt < 4; nt++)
#pragma unroll
      for (int j = 0; j < 4; j++) acc[nt][j] *= alpha[j];

    // P -> LDS (bf16) for PV A-operand (wave-local rows)
#pragma unroll
    for (int kt = 0; kt < 4; kt++)
#pragma unroll
      for (int j = 0; j < 4; j++)
        P_lds[(wv * 16 + bq * 4 + j) * LSTR + kt * 16 + r] = f2bf(s[kt][j]);
    __syncthreads();

    // PV: acc += P V
    U8 pa0, pa1;
    const unsigned short* pp = &P_lds[(wv * 16 + r) * LSTR + bq * 8];
    pa0.u = *(const us8*)pp;
    pa1.u = *(const us8*)(pp + 32);
#pragma unroll
    for (int nt = 0; nt < 4; nt++) {
      const unsigned short* vp = &VT_lds[(nt * 16 + r) * LSTR + bq * 8];
      U8 v0, v1;
      v0.u = *(const us8*)vp;
      v1.u = *(const us8*)(vp + 32);
      acc[nt] = MFMA16(pa0.b, v0.b, acc[nt]);
      acc[nt] = MFMA16(pa1.b, v1.b, acc[nt]);
    }
  }

  float rl[4];
#pragma unroll
  for (int j = 0; j < 4; j++) rl[j] = lrun[j] > 0.f ? 1.f / lrun[j] : 0.f;
#pragma unroll
  for (int nt = 0; nt < 4; nt++)
#pragma unroll
    for (int j = 0; j < 4; j++)
      out[(base + q0 + wv * 16 + bq * 4 + j) * Hn + nt * 16 + r] =
          acc[nt][j] * rl[j];
}

// ---------------------------------------------------------------------------
extern "C" void kernel_launch(void* const* d_in, const int* in_sizes, int n_in,
                              void* d_out, int out_size, void* d_ws, size_t ws_size,
                              hipStream_t stream) {
  const float* x  = (const float*)d_in[0];
  const int* am   = (const int*)d_in[1];
  const float* Wk = (const float*)d_in[2];
  const float* Wq = (const float*)d_in[3];
  const float* Wv = (const float*)d_in[4];
  float* out = (float*)d_out;

  // ws layout: WT bf16 [192][768] | q bf16 [Mn][64] | k | v   (~6.3 MB)
  unsigned short* WT  = (unsigned short*)d_ws;
  unsigned short* qkv = WT + 192 * Cn;

  wt_prep<<<192, 256, 0, stream>>>(Wq, Wk, Wv, WT);
  proj<<<Mn / 64, 256, 0, stream>>>(x, WT, qkv);
  attn<<<dim3(Tn / 64, Bn), 256, 0, stream>>>(qkv, am, out);
}

// Round 5
// 180.086 us; speedup vs baseline: 1.5541x; 1.5541x over previous
//
#include <hip/hip_runtime.h>

// Problem constants (B,T,C,H) = (4, 4096, 768, 64)
#define Bn 4
#define Tn 4096
#define Cn 768
#define Hn 64
#define Mn (Bn * Tn)                    // 16384 rows
#define SCALE_ 0.036084391824351615f    // 768^-0.5  (reference scales by C^-0.5)

typedef __bf16 bf16x8 __attribute__((ext_vector_type(8)));
typedef float f32x4 __attribute__((ext_vector_type(4)));
typedef unsigned short us8 __attribute__((ext_vector_type(8)));

union U8 { us8 u; bf16x8 b; };

#define MFMA16(a, b, c) __builtin_amdgcn_mfma_f32_16x16x32_bf16((a), (b), (c), 0, 0, 0)

__device__ __forceinline__ unsigned short f2bf(float f) {
  unsigned u = __float_as_uint(f);
  u += 0x7fffu + ((u >> 16) & 1u);   // round-to-nearest-even
  return (unsigned short)(u >> 16);
}

// ---------------------------------------------------------------------------
// Kernel 0: WT[n][c] bf16, n in [0,192): 0-63 = Wq cols, 64-127 = Wk, 128-191 = Wv
// ---------------------------------------------------------------------------
__global__ __launch_bounds__(256) void wt_prep(const float* __restrict__ Wq,
                                               const float* __restrict__ Wk,
                                               const float* __restrict__ Wv,
                                               unsigned short* __restrict__ WT) {
  int n = blockIdx.x;  // 0..191
  const float* src = (n < 64) ? Wq : (n < 128) ? Wk : Wv;
  int h = n & 63;
  for (int c = threadIdx.x; c < Cn; c += 256)
    WT[n * Cn + c] = f2bf(src[c * Hn + h]);
}

// ---------------------------------------------------------------------------
// Kernel 1: QKV projection. grid = Mn/32 = 512 blocks x 256 thr (4 waves).
// Block: 32 rows x 192 cols. x staged once to LDS (fp32->bf16, XOR swizzle
// col' = c ^ 8*(row&7) -> conflict-free b128 frag reads). Wave wv: 48 cols
// (3 nt tiles) x both 16-row tiles -> B loads amortized over 2 MFMAs.
// ---------------------------------------------------------------------------
__global__ __launch_bounds__(256) void proj(const float* __restrict__ x,
                                            const unsigned short* __restrict__ WT,
                                            unsigned short* __restrict__ qkv) {
  __shared__ unsigned short a_lds[32 * Cn];
  int tid = threadIdx.x;
  int wv = tid >> 6, lane = tid & 63, r = lane & 15, bq = lane >> 4;
  int m0 = blockIdx.x * 32;

  // stage 32 rows x 768 fp32 -> bf16 LDS (3072 us8-chunks, 12/thread)
#pragma unroll
  for (int i = 0; i < 12; i++) {
    int q = tid + 256 * i;
    int rr = q / 96, cw = q % 96;
    const float* p = x + (long)(m0 + rr) * Cn + cw * 8;
    f32x4 f0 = *(const f32x4*)p;
    f32x4 f1 = *(const f32x4*)(p + 4);
    us8 uu;
    uu[0] = f2bf(f0[0]); uu[1] = f2bf(f0[1]); uu[2] = f2bf(f0[2]); uu[3] = f2bf(f0[3]);
    uu[4] = f2bf(f1[0]); uu[5] = f2bf(f1[1]); uu[6] = f2bf(f1[2]); uu[7] = f2bf(f1[3]);
    *(us8*)&a_lds[rr * Cn + ((cw * 8) ^ ((rr & 7) << 3))] = uu;
  }
  __syncthreads();

  f32x4 acc[2][3];
#pragma unroll
  for (int mt = 0; mt < 2; mt++)
#pragma unroll
    for (int nt = 0; nt < 3; nt++) acc[mt][nt] = (f32x4){0.f, 0.f, 0.f, 0.f};

  int n0 = wv * 48;
  for (int kc = 0; kc < 12; kc++) {
    U8 a[2][2];
#pragma unroll
    for (int mt = 0; mt < 2; mt++) {
      int rr = mt * 16 + r;
      int sw = (rr & 7) << 3;
#pragma unroll
      for (int ks = 0; ks < 2; ks++)
        a[mt][ks].u = *(const us8*)&a_lds[rr * Cn + kc * 64 + ((ks * 32 + bq * 8) ^ sw)];
    }
#pragma unroll
    for (int nt = 0; nt < 3; nt++) {
      const unsigned short* wp = WT + (long)(n0 + nt * 16 + r) * Cn + kc * 64 + bq * 8;
      U8 b0, b1;
      b0.u = *(const us8*)wp;
      b1.u = *(const us8*)(wp + 32);
#pragma unroll
      for (int mt = 0; mt < 2; mt++) {
        acc[mt][nt] = MFMA16(a[mt][0].b, b0.b, acc[mt][nt]);
        acc[mt][nt] = MFMA16(a[mt][1].b, b1.b, acc[mt][nt]);
      }
    }
  }
#pragma unroll
  for (int mt = 0; mt < 2; mt++)
#pragma unroll
    for (int nt = 0; nt < 3; nt++) {
      int col = n0 + nt * 16 + r;
      unsigned short* outp = qkv + (long)(col >> 6) * Mn * Hn;  // 0:q 1:k 2:v
      int ncol = col & 63;
#pragma unroll
      for (int j = 0; j < 4; j++) {
        int m = m0 + mt * 16 + bq * 4 + j;
        outp[(long)m * Hn + ncol] = f2bf(acc[mt][nt][j]);
      }
    }
}

// ---------------------------------------------------------------------------
// Kernel 2: flash attention, split-K. grid (Tn/64, Bn, S) x 256 thr.
// Block: 64 q-rows x span keys (span = Tn/S), KV tiles of 64 in LDS.
// VT staged with XOR swizzle: V[k][n] at n*LSTR + (k ^ 8*(n>>3)) -> write
// banks spread over all 32 (was 16-way conflict), reads stay 16B-contiguous.
// Partial (unnormalized acc, m, l) to workspace; merged by merge kernel.
// ---------------------------------------------------------------------------
#define LSTR 88

__global__ __launch_bounds__(256) void attn(const unsigned short* __restrict__ qkv,
                                            const int* __restrict__ amask,
                                            float* __restrict__ pacc,
                                            float* __restrict__ pm,
                                            float* __restrict__ pl,
                                            int span) {
  __shared__ unsigned short K_lds[64 * LSTR];
  __shared__ unsigned short VT_lds[64 * LSTR];
  __shared__ unsigned short P_lds[64 * LSTR];
  __shared__ int m_lds[64];

  int tid = threadIdx.x;
  int wv = tid >> 6, lane = tid & 63, r = lane & 15, bq = lane >> 4;
  int qt = blockIdx.x, bidx = blockIdx.y, sp = blockIdx.z;
  int q0 = qt * 64;
  long base = (long)bidx * Tn;

  const unsigned short* q_ws = qkv;
  const unsigned short* k_ws = qkv + (long)Mn * Hn;
  const unsigned short* v_ws = qkv + 2L * Mn * Hn;

  U8 qf[2];
  {
    const unsigned short* qp = q_ws + (base + q0 + wv * 16 + r) * Hn + bq * 8;
    qf[0].u = *(const us8*)qp;
    qf[1].u = *(const us8*)(qp + 32);
  }

  float mrun[4], lrun[4];
  f32x4 acc[4];
#pragma unroll
  for (int j = 0; j < 4; j++) { mrun[j] = -1e30f; lrun[j] = 0.f; }
#pragma unroll
  for (int nt = 0; nt < 4; nt++) acc[nt] = (f32x4){0.f, 0.f, 0.f, 0.f};

  int kv_beg = sp * span, kv_end = kv_beg + span;
  for (int kv0 = kv_beg; kv0 < kv_end; kv0 += 64) {
    __syncthreads();  // prior PV reads done before restage
#pragma unroll
    for (int it = 0; it < 2; it++) {
      int vid = tid + it * 256;
      int row = vid >> 3, cb = vid & 7;
      *(us8*)(&K_lds[row * LSTR + cb * 8]) =
          *(const us8*)(k_ws + (base + kv0 + row) * Hn + cb * 8);
      us8 vvv = *(const us8*)(v_ws + (base + kv0 + row) * Hn + cb * 8);
      int xr = row ^ (cb << 3);   // swizzled row index (col>>3 == cb)
#pragma unroll
      for (int e = 0; e < 8; e++)
        VT_lds[(cb * 8 + e) * LSTR + xr] = vvv[e];
    }
    if (tid < 64) m_lds[tid] = amask[base + kv0 + tid];
    __syncthreads();

    // S = Q K^T
    f32x4 s[4];
#pragma unroll
    for (int kt = 0; kt < 4; kt++) {
      const unsigned short* kp = &K_lds[(kt * 16 + r) * LSTR + bq * 8];
      U8 b0, b1;
      b0.u = *(const us8*)kp;
      b1.u = *(const us8*)(kp + 32);
      f32x4 z = (f32x4){0.f, 0.f, 0.f, 0.f};
      z = MFMA16(qf[0].b, b0.b, z);
      z = MFMA16(qf[1].b, b1.b, z);
      s[kt] = z;
    }

    float pmax[4];
#pragma unroll
    for (int j = 0; j < 4; j++) pmax[j] = -3.0e38f;
#pragma unroll
    for (int kt = 0; kt < 4; kt++) {
      bool dead = (m_lds[kt * 16 + r] == 0);
#pragma unroll
      for (int j = 0; j < 4; j++) {
        float sv = dead ? -3.0e38f : s[kt][j] * SCALE_;
        s[kt][j] = sv;
        pmax[j] = fmaxf(pmax[j], sv);
      }
    }
#pragma unroll
    for (int j = 0; j < 4; j++) {
      pmax[j] = fmaxf(pmax[j], __shfl_xor(pmax[j], 1));
      pmax[j] = fmaxf(pmax[j], __shfl_xor(pmax[j], 2));
      pmax[j] = fmaxf(pmax[j], __shfl_xor(pmax[j], 4));
      pmax[j] = fmaxf(pmax[j], __shfl_xor(pmax[j], 8));
    }
    float alpha[4], ps[4];
#pragma unroll
    for (int j = 0; j < 4; j++) {
      float mn = fmaxf(mrun[j], pmax[j]);
      alpha[j] = __expf(mrun[j] - mn);
      mrun[j] = mn;
      ps[j] = 0.f;
    }
#pragma unroll
    for (int kt = 0; kt < 4; kt++)
#pragma unroll
      for (int j = 0; j < 4; j++) {
        float p = __expf(s[kt][j] - mrun[j]);
        s[kt][j] = p;
        ps[j] += p;
      }
#pragma unroll
    for (int j = 0; j < 4; j++) {
      ps[j] += __shfl_xor(ps[j], 1);
      ps[j] += __shfl_xor(ps[j], 2);
      ps[j] += __shfl_xor(ps[j], 4);
      ps[j] += __shfl_xor(ps[j], 8);
      lrun[j] = lrun[j] * alpha[j] + ps[j];
    }
#pragma unroll
    for (int nt = 0; nt < 4; nt++)
#pragma unroll
      for (int j = 0; j < 4; j++) acc[nt][j] *= alpha[j];

    // P -> LDS (wave-private rows; no barrier needed before PV)
#pragma unroll
    for (int kt = 0; kt < 4; kt++)
#pragma unroll
      for (int j = 0; j < 4; j++)
        P_lds[(wv * 16 + bq * 4 + j) * LSTR + kt * 16 + r] = f2bf(s[kt][j]);

    U8 pa0, pa1;
    const unsigned short* pp = &P_lds[(wv * 16 + r) * LSTR + bq * 8];
    pa0.u = *(const us8*)pp;
    pa1.u = *(const us8*)(pp + 32);
#pragma unroll
    for (int nt = 0; nt < 4; nt++) {
      int col = nt * 16 + r;
      int sw = (col >> 3) << 3;
      U8 v0, v1;
      v0.u = *(const us8*)&VT_lds[col * LSTR + ((bq * 8) ^ sw)];
      v1.u = *(const us8*)&VT_lds[col * LSTR + ((32 + bq * 8) ^ sw)];
      acc[nt] = MFMA16(pa0.b, v0.b, acc[nt]);
      acc[nt] = MFMA16(pa1.b, v1.b, acc[nt]);
    }
  }

  // write partials (unnormalized)
  long pb = ((long)sp * Bn + bidx) * 64 + qt;
  float* accp = pacc + pb * 4096;
#pragma unroll
  for (int nt = 0; nt < 4; nt++)
#pragma unroll
    for (int j = 0; j < 4; j++)
      accp[(wv * 16 + bq * 4 + j) * 64 + nt * 16 + r] = acc[nt][j];
  if (r == 0) {
#pragma unroll
    for (int j = 0; j < 4; j++) {
      int row = wv * 16 + bq * 4 + j;
      pm[pb * 64 + row] = mrun[j];
      pl[pb * 64 + row] = lrun[j];
    }
  }
}

// ---------------------------------------------------------------------------
// Kernel 3: merge split-K partials. grid (64, Bn) x 256 thr.
// thread: row = tid>>2, 16 cols at (tid&3)*16.
// ---------------------------------------------------------------------------
__global__ __launch_bounds__(256) void merge(const float* __restrict__ pacc,
                                             const float* __restrict__ pm,
                                             const float* __restrict__ pl,
                                             float* __restrict__ out, int S) {
  int qt = blockIdx.x, bidx = blockIdx.y;
  int tid = threadIdx.x;
  int row = tid >> 2, c0 = (tid & 3) * 16;

  float M = -3.0e38f;
  for (int s = 0; s < S; s++) {
    long pb = ((long)s * Bn + bidx) * 64 + qt;
    M = fmaxf(M, pm[pb * 64 + row]);
  }
  float L = 0.f;
  f32x4 o[4];
#pragma unroll
  for (int c = 0; c < 4; c++) o[c] = (f32x4){0.f, 0.f, 0.f, 0.f};
  for (int s = 0; s < S; s++) {
    long pb = ((long)s * Bn + bidx) * 64 + qt;
    float w = __expf(pm[pb * 64 + row] - M);
    L += w * pl[pb * 64 + row];
    const float* ap = pacc + pb * 4096 + row * 64 + c0;
#pragma unroll
    for (int c = 0; c < 4; c++) {
      f32x4 a = *(const f32x4*)(ap + c * 4);
#pragma unroll
      for (int e = 0; e < 4; e++) o[c][e] += w * a[e];
    }
  }
  float rl = L > 0.f ? 1.f / L : 0.f;
  float* op = out + ((long)bidx * Tn + qt * 64 + row) * 64 + c0;
#pragma unroll
  for (int c = 0; c < 4; c++) {
    f32x4 v;
#pragma unroll
    for (int e = 0; e < 4; e++) v[e] = o[c][e] * rl;
    *(f32x4*)(op + c * 4) = v;
  }
}

// ---------------------------------------------------------------------------
extern "C" void kernel_launch(void* const* d_in, const int* in_sizes, int n_in,
                              void* d_out, int out_size, void* d_ws, size_t ws_size,
                              hipStream_t stream) {
  const float* x  = (const float*)d_in[0];
  const int* am   = (const int*)d_in[1];
  const float* Wk = (const float*)d_in[2];
  const float* Wq = (const float*)d_in[3];
  const float* Wv = (const float*)d_in[4];
  float* out = (float*)d_out;

  // ws: WT bf16 [192][768] | qkv bf16 3x[Mn][64] | pacc f32 | pm | pl
  size_t off_wt   = 0;
  size_t off_qkv  = off_wt + (size_t)192 * Cn * 2;            // 294912
  size_t off_pacc = off_qkv + (size_t)3 * Mn * Hn * 2;        // +6291456
  // per-split partial bytes: acc 4*64*4096*4 + m/l 2*4*64*64*4
  size_t per_split = (size_t)Bn * 64 * 4096 * 4 + (size_t)2 * Bn * 64 * 64 * 4;
  int S = 4;
  while (S > 1 && off_pacc + (size_t)S * per_split > ws_size) S >>= 1;
  size_t acc_bytes = (size_t)S * Bn * 64 * 4096 * 4;

  unsigned short* WT  = (unsigned short*)((char*)d_ws + off_wt);
  unsigned short* qkv = (unsigned short*)((char*)d_ws + off_qkv);
  float* pacc = (float*)((char*)d_ws + off_pacc);
  float* pm   = (float*)((char*)d_ws + off_pacc + acc_bytes);
  float* pl   = pm + (size_t)S * Bn * 64 * 64;

  wt_prep<<<192, 256, 0, stream>>>(Wq, Wk, Wv, WT);
  proj<<<Mn / 32, 256, 0, stream>>>(x, WT, qkv);
  attn<<<dim3(Tn / 64, Bn, S), 256, 0, stream>>>(qkv, am, pacc, pm, pl, Tn / S);
  merge<<<dim3(64, Bn), 256, 0, stream>>>(pacc, pm, pl, out, S);
}